// Round 12
// baseline (232.615 us; speedup 1.0000x reference)
//
#include <hip/hip_runtime.h>
#include <hip/hip_fp16.h>

#define N_NODES 50000
#define N_EDGES 800000
#define F_INN   128
#define F_HID   96
#define F_OUTT  40
#define SLOTS   64    // padded-CSR slots/node; P(deg>=64 | Poisson(16)) ~ 2e-18

// Feature-sliced T/H layout: 4 slices x 24 features. Slice s holds features
// [24s,24s+24) for ALL nodes contiguously: 50000 x 48B = 2.4MB per slice ->
// fits one XCD's 4MB L2.  24 = 3x8 so 8-feature GEMM chunks never cross a
// slice boundary.  (Indexing verified in R2, absmax 2.4e-4.)
#define SL_HALVES (N_NODES * 24)   // halves per slice  (1,200,000)
#define SL_F4     (N_NODES * 3)    // float4s per slice (150,000)
#define NGRP      3125             // 16-node groups (50000/16, exact)

typedef _Float16 half8 __attribute__((ext_vector_type(8)));
typedef float    floatx4 __attribute__((ext_vector_type(4)));

// ---------------------------------------------------------------------------
// MFMA GEMM body: T(sliced fp16) = X[n x FI] @ W, via 16x16x32 f16.
// TIN=float: dense input rows (x).  TIN=__half: sliced fp16 input (H).
// SCALE: multiply output row by dinv[node] (fp32) before the fp16 store.
// LDS: single 26112B buffer; BT tile, then reused as OUT staging (6 blk/CU).
// ---------------------------------------------------------------------------
template <int FI, typename TIN, bool SCALE>
__device__ __forceinline__ void mfma_gemm_body(
        const TIN* __restrict__ X, const __half* __restrict__ BTg,
        const float* __restrict__ dinv, float4* __restrict__ Th4, int n, int bx) {
    __shared__ __half BTl[96 * 136];          // 26112 B; reused as OUT staging
    __half* OUTl = BTl;
    int tid = threadIdx.x;
    {   // stage BT (1632 x 16B)
        const int4* s = reinterpret_cast<const int4*>(BTg);
        int4* d = reinterpret_cast<int4*>(BTl);
        for (int i = tid; i < 96 * 136 / 8; i += 256) d[i] = s[i];
    }
    __syncthreads();

    int lane = tid & 63, w = tid >> 6;
    int lm = lane & 15, q = lane >> 4;
    int base = bx * 64 + w * 16;
    int node = base + lm;
    int nclamp = min(node, n - 1);

    floatx4 cf[6];
    #pragma unroll
    for (int t = 0; t < 6; ++t) cf[t] = (floatx4){0.f, 0.f, 0.f, 0.f};

    constexpr int KS = FI / 32;
    #pragma unroll
    for (int ks = 0; ks < KS; ++ks) {
        half8 bv;
        if constexpr (sizeof(TIN) == 4) {
            const float4* xr = reinterpret_cast<const float4*>(
                X + (size_t)nclamp * FI + 32 * ks + q * 8);
            float4 f0 = xr[0], f1 = xr[1];
            union { half8 v; __half2 h[4]; } b;
            b.h[0] = __floats2half2_rn(f0.x, f0.y);
            b.h[1] = __floats2half2_rn(f0.z, f0.w);
            b.h[2] = __floats2half2_rn(f1.x, f1.y);
            b.h[3] = __floats2half2_rn(f1.z, f1.w);
            bv = b.v;
        } else {
            // sliced fp16 input: chunk c8 = 4*ks+q -> slice c8/3, offset c8%3
            int c8 = 4 * ks + q;
            int sl = c8 / 3, of8 = c8 - sl * 3;
            bv = *reinterpret_cast<const half8*>(
                reinterpret_cast<const _Float16*>(X) +
                (size_t)sl * SL_HALVES + (size_t)nclamp * 24 + of8 * 8);
        }
        #pragma unroll
        for (int t = 0; t < 6; ++t) {
            half8 a = *reinterpret_cast<const half8*>(
                &BTl[(t * 16 + lm) * 136 + q * 8 + 32 * ks]);
            cf[t] = __builtin_amdgcn_mfma_f32_16x16x32_f16(a, bv, cf[t], 0, 0, 0);
        }
    }

    float dv = 1.0f;
    if constexpr (SCALE) dv = dinv[nclamp];

    __syncthreads();   // all waves done reading BTl; safe to reuse as OUTl

    __half* orow = OUTl + (w * 16 + lm) * 104;
    #pragma unroll
    for (int t = 0; t < 6; ++t) {
        union { int2 i2; __half2 h[2]; } u;
        u.h[0] = __floats2half2_rn(dv * cf[t][0], dv * cf[t][1]);
        u.h[1] = __floats2half2_rn(dv * cf[t][2], dv * cf[t][3]);
        *reinterpret_cast<int2*>(&orow[t * 16 + q * 4]) = u.i2;
    }
    // Sliced fp16 store: chunk c -> slice c/3 (12 x float4 per node).
    #pragma unroll
    for (int R = 0; R < 3; ++R) {
        int nl = lane >> 2, c = (lane & 3) + 4 * R;
        int sl = c / 3, of8 = c - sl * 3;
        float4 v = *reinterpret_cast<const float4*>(&OUTl[(w * 16 + nl) * 104 + c * 8]);
        int gn = base + nl;
        if (gn < n) Th4[(size_t)sl * SL_F4 + (size_t)gn * 3 + of8] = v;
    }
}

// ---------------------------------------------------------------------------
// Fused: count (blocks [0,nCB)) + gemm L1 (blocks [nCB,..)) — independent.
// Count: 2 edges/thread, returning atomics, coalesced rank store (rank IS the
// padded-CSR slot).  ~45us device-atomic floor (R4-R8); rides with gemm1.
// ---------------------------------------------------------------------------
__global__ __launch_bounds__(256) void count_gemm1_kernel(
        const int* __restrict__ dst, int* __restrict__ cnt, int* __restrict__ rank,
        int e, const float* __restrict__ X, const __half* __restrict__ BT1,
        float4* __restrict__ Th4, int n, int nCB) {
    if ((int)blockIdx.x < nCB) {
        int i = blockIdx.x * 512 + threadIdx.x;
        int j = i + 256;
        bool bi = i < e, bj = j < e;
        int di = 0, dj = 0, ri, rj;
        if (bi) di = dst[i];
        if (bj) dj = dst[j];
        if (bi) ri = atomicAdd(&cnt[di], 1);
        if (bj) rj = atomicAdd(&cnt[dj], 1);
        if (bi) rank[i] = ri;
        if (bj) rank[j] = rj;
    } else {
        mfma_gemm_body<F_INN, float, false>(X, BT1, nullptr, Th4, n, blockIdx.x - nCB);
    }
}

template <int FI, typename TIN, bool SCALE>
__global__ __launch_bounds__(256) void mfma_gemm_kernel(
        const TIN* __restrict__ X, const __half* __restrict__ BTg,
        const float* __restrict__ dinv, float4* __restrict__ Th4, int n) {
    mfma_gemm_body<FI, TIN, SCALE>(X, BTg, dinv, Th4, n, blockIdx.x);
}

// ---------------------------------------------------------------------------
// Fused prep: zero cnt + weight transpose/fp16 (W1 & W2) — one dispatch.
// ---------------------------------------------------------------------------
__global__ void wt_zero_kernel(const float* __restrict__ W1, const float* __restrict__ W2,
                               __half* __restrict__ BT1, __half* __restrict__ BT2,
                               int* __restrict__ cnt) {
    int i = blockIdx.x * 256 + threadIdx.x;
    if (i < N_NODES) cnt[i] = 0;
    if (i < 96 * 128) {
        int j = i / 128, k = i - j * 128;
        BT1[j * 136 + k] = __float2half(W1[k * 96 + j]);
    } else if (i < 96 * 128 + 96 * 96) {
        int t = i - 96 * 128;
        int j = t / 96, k = t - j * 96;
        BT2[j * 136 + k] = __float2half(W2[k * 96 + j]);
    }
}

// ---------------------------------------------------------------------------
// Fused: atomic-free padded-CSR fill (blocks [0,nFB)) + dinv/T pre-scale
// (blocks [nFB,..)).  Fill: csr_pad[dst*64 + rank] = src.  Scale: over the
// SLICED T array — node of float4 i is (i % (N*3)) / 3.
// ---------------------------------------------------------------------------
__global__ __launch_bounds__(256) void fill_scale_kernel(
        const int* __restrict__ src, const int* __restrict__ dst,
        const int* __restrict__ rank, int* __restrict__ csr_pad,
        const int* __restrict__ cnt, float* __restrict__ dinv,
        float4* __restrict__ Th4, int e, int n, int nFB) {
    if ((int)blockIdx.x < nFB) {
        int i = blockIdx.x * 256 + threadIdx.x;
        if (i >= e) return;
        int r = rank[i];
        if (r < SLOTS) csr_pad[dst[i] * SLOTS + r] = src[i];
    } else {
        int i = (blockIdx.x - nFB) * 256 + threadIdx.x;   // flat float4 index
        if (i < n) dinv[i] = rsqrtf((float)min(cnt[i], SLOTS) + 1.0f);
        if (i >= n * 12) return;
        int rem = i % (n * 3);
        int node = rem / 3;
        float s = rsqrtf((float)min(cnt[node], SLOTS) + 1.0f);
        union { float4 f4; __half2 h[4]; } u;
        u.f4 = Th4[i];
        #pragma unroll
        for (int q = 0; q < 4; ++q) {
            float2 t = __half22float2(u.h[q]);
            u.h[q] = __floats2half2_rn(s * t.x, s * t.y);
        }
        Th4[i] = u.f4;
    }
}

// ---------------------------------------------------------------------------
// DPP row_shl helper: lane i reads lane i+N within its 16-lane row; 0 if OOB.
// ---------------------------------------------------------------------------
template <int N>
__device__ __forceinline__ float dpp_shl(float x) {
    return __int_as_float(__builtin_amdgcn_update_dpp(
        0, __float_as_int(x), 0x100 + N, 0xF, 0xF, true));
}

// ---------------------------------------------------------------------------
// Sliced aggregation.  Block = (slice, 16-node group): 4 waves x 4 nodes.
// Per node: 16 lanes = 5 edge slots x 3 chunks (16B, 48B = slice row) + 1
// idle.  slice = (bid%8)>>1 -> each XCD pair's gathers stay inside ONE 2.4MB
// slice (L2-resident; bid%8->XCD round-robin per measured HK swizzle).
// T is PRE-SCALED (dinv[s]*T[s]) so edge weight is 1 (0 for pad); self-loop
// is virtual position -1 reading the node's own row.  Slot reduction via DPP
// row_shl (no LDS).  H[d] = relu(dinv[d]*tot + b), fp16 sliced out.
// ---------------------------------------------------------------------------
__global__ __launch_bounds__(256) void agg_kernel(
        const __half* __restrict__ T, const int* __restrict__ cnt,
        const int* __restrict__ csr_pad, const float* __restrict__ dinv,
        const float* __restrict__ bias, __half* __restrict__ H, int n) {
    int bid = blockIdx.x;
    int xr = bid & 7, m = bid >> 3;
    int s  = xr >> 1;                       // feature slice 0..3 (per XCD pair)
    int grp = m * 2 + (xr & 1);             // 16-node group
    if (grp >= NGRP) return;

    int tid = threadIdx.x, lane = tid & 63, wid = tid >> 6;
    int e5 = lane & 15;
    int e  = e5 / 3;                        // edge slot 0..4 (e5==15 -> idle)
    int g  = e5 - e * 3;                    // 16B chunk within 48B slice row
    bool act = e5 < 15;

    int node = grp * 16 + wid * 4 + (lane >> 4);
    float dn = dinv[node];
    const int* row = csr_pad + (size_t)node * SLOTS;
    int deg = min(cnt[node], SLOTS);
    const _Float16* Ts = reinterpret_cast<const _Float16*>(T) + (size_t)s * SL_HALVES;

    float acc[8];
    #pragma unroll
    for (int t = 0; t < 8; ++t) acc[t] = 0.f;

    auto ROUND = [&](int q) {
        int sn = node; float w = 0.f;
        if (act) {
            if (q >= 0 && q < deg) { sn = row[q]; w = 1.f; }
            else if (q == -1)      { w = 1.f; }   // self-loop (e==0 only)
        }
        union { half8 v; __half2 h[4]; } u;
        u.v = *reinterpret_cast<const half8*>(Ts + (size_t)sn * 24 + g * 8);
        #pragma unroll
        for (int t = 0; t < 4; ++t) {
            float2 f = __half22float2(u.h[t]);
            acc[2 * t]     = fmaf(w, f.x, acc[2 * t]);
            acc[2 * t + 1] = fmaf(w, f.y, acc[2 * t + 1]);
        }
    };
    int p = -1 + e;
    do { ROUND(p); ROUND(p + 5); p += 10; } while (__any(act && p < deg));

    // Reduce the 5 edge slots (stride 3 in each 16-lane row): totals at e5=0..2.
    float tot[8];
    #pragma unroll
    for (int t = 0; t < 8; ++t) {
        float v1 = acc[t] + dpp_shl<3>(acc[t]);
        float v2 = v1 + dpp_shl<6>(v1);
        tot[t] = v2 + dpp_shl<12>(acc[t]);
    }

    if (e5 < 3) {
        const float4* bp = reinterpret_cast<const float4*>(bias + s * 24 + e5 * 8);
        float4 b0 = bp[0], b1 = bp[1];
        union { int4 i4; __half2 h[4]; } o;
        o.h[0] = __floats2half2_rn(fmaxf(fmaf(dn, tot[0], b0.x), 0.f),
                                   fmaxf(fmaf(dn, tot[1], b0.y), 0.f));
        o.h[1] = __floats2half2_rn(fmaxf(fmaf(dn, tot[2], b0.z), 0.f),
                                   fmaxf(fmaf(dn, tot[3], b0.w), 0.f));
        o.h[2] = __floats2half2_rn(fmaxf(fmaf(dn, tot[4], b1.x), 0.f),
                                   fmaxf(fmaf(dn, tot[5], b1.y), 0.f));
        o.h[3] = __floats2half2_rn(fmaxf(fmaf(dn, tot[6], b1.z), 0.f),
                                   fmaxf(fmaf(dn, tot[7], b1.w), 0.f));
        *reinterpret_cast<int4*>(
            H + (size_t)s * SL_HALVES + (size_t)node * 24 + e5 * 8) = o.i4;
    }
}

// ---------------------------------------------------------------------------
// Output GEMM: out[n x 40] = H[n x 96](fp16, SLICED) @ W[96 x 40] + bias.
// ---------------------------------------------------------------------------
__global__ __launch_bounds__(320) void gemm_out_kernel(
        const __half* __restrict__ A, const float* __restrict__ W,
        const float* __restrict__ bias, float* __restrict__ C, int n) {
    __shared__ float Wlds[96 * 40];
    int tid = threadIdx.y * 10 + threadIdx.x;
    for (int i = tid; i < 96 * 10; i += 320)
        reinterpret_cast<float4*>(Wlds)[i] = reinterpret_cast<const float4*>(W)[i];
    __syncthreads();

    int j    = threadIdx.x * 4;
    int node = blockIdx.x * 32 + threadIdx.y;
    int nc   = min(node, n - 1);
    float4 acc = make_float4(0.f, 0.f, 0.f, 0.f);
    #pragma unroll
    for (int c8 = 0; c8 < 12; ++c8) {            // 8-feature chunk; f = 8*c8
        int sl = c8 / 3, of8 = c8 - sl * 3;      // compile-time (unrolled)
        union { int4 i4; __half2 h[4]; } u;
        u.i4 = *reinterpret_cast<const int4*>(
            A + (size_t)sl * SL_HALVES + (size_t)nc * 24 + of8 * 8);
        #pragma unroll
        for (int t = 0; t < 4; ++t) {
            float2 a = __half22float2(u.h[t]);
            int k = c8 * 8 + 2 * t;
            float4 w0 = *reinterpret_cast<const float4*>(Wlds + k * 40 + j);
            float4 w1 = *reinterpret_cast<const float4*>(Wlds + (k + 1) * 40 + j);
            acc.x += a.x * w0.x + a.y * w1.x;
            acc.y += a.x * w0.y + a.y * w1.y;
            acc.z += a.x * w0.z + a.y * w1.z;
            acc.w += a.x * w0.w + a.y * w1.w;
        }
    }
    if (node < n) {
        float4 b = *reinterpret_cast<const float4*>(bias + j);
        acc.x += b.x; acc.y += b.y; acc.z += b.z; acc.w += b.w;
        *reinterpret_cast<float4*>(C + (size_t)node * 40 + j) = acc;
    }
}

// ---------------------------------------------------------------------------

extern "C" void kernel_launch(void* const* d_in, const int* in_sizes, int n_in,
                              void* d_out, int out_size, void* d_ws, size_t ws_size,
                              hipStream_t stream) {
    const float* x    = (const float*)d_in[0];
    const int*   ei   = (const int*)d_in[1];
    const float* W1   = (const float*)d_in[2];
    const float* b1   = (const float*)d_in[3];
    const float* W2   = (const float*)d_in[4];
    const float* b2   = (const float*)d_in[5];
    const float* Wout = (const float*)d_in[6];
    const float* bout = (const float*)d_in[7];
    float*       out  = (float*)d_out;

    const int* src = ei;            // edge_index[0]
    const int* dst = ei + N_EDGES;  // edge_index[1]

    char* ws = (char*)d_ws;
    size_t off = 0;
    auto alloc = [&](size_t bytes) {
        size_t o = off;
        off = (off + bytes + 511) & ~(size_t)511;
        return (void*)(ws + o);
    };
    int*     cnt     = (int*)    alloc((size_t)N_NODES * sizeof(int));
    float*   dinv    = (float*)  alloc(N_NODES * sizeof(float));
    int*     rank    = (int*)    alloc((size_t)N_EDGES * sizeof(int));
    int*     csr_pad = (int*)    alloc((size_t)N_NODES * SLOTS * sizeof(int));
    __half*  BT1     = (__half*) alloc((size_t)96 * 136 * sizeof(__half));
    __half*  BT2     = (__half*) alloc((size_t)96 * 136 * sizeof(__half));
    __half*  Th      = (__half*) alloc((size_t)N_NODES * 96 * sizeof(__half));
    __half*  Hh      = (__half*) alloc((size_t)N_NODES * 96 * sizeof(__half));

    const int CB2 = (N_EDGES + 511) / 512;       // 1563 count blocks
    const int FB  = (N_EDGES + 255) / 256;       // 3125 fill blocks
    const int SB  = (N_NODES * 12 + 255) / 256;  // 2344 scale blocks
    const int GB  = (N_NODES + 63) / 64;         // 782 gemm blocks
    const int AGB = ((NGRP + 1) / 2) * 8;        // 12504 sliced-agg blocks

    // --- prep: zero cnt + weight transpose, one dispatch ---
    wt_zero_kernel<<<(N_NODES + 255) / 256, 256, 0, stream>>>(W1, W2, BT1, BT2, cnt);

    // --- fused: edge count (rank = slot) + layer-1 GEMM (sliced out) ---
    count_gemm1_kernel<<<CB2 + GB, 256, 0, stream>>>(
        dst, cnt, rank, N_EDGES, x, BT1, (float4*)Th, N_NODES, CB2);

    // --- fused: atomic-free CSR fill + dinv/T pre-scale ---
    fill_scale_kernel<<<FB + SB, 256, 0, stream>>>(
        src, dst, rank, csr_pad, cnt, dinv, (float4*)Th, N_EDGES, N_NODES, FB);

    // --- layer 1 aggregation (sliced, XCD-affine) -> H ---
    agg_kernel<<<AGB, 256, 0, stream>>>(Th, cnt, csr_pad, dinv, b1, Hh, N_NODES);

    // --- layer 2: GEMM (sliced in/out, dinv-scaled) + aggregation ---
    mfma_gemm_kernel<F_HID, __half, true><<<GB, 256, 0, stream>>>(
        (const __half*)Hh, BT2, dinv, (float4*)Th, N_NODES);
    agg_kernel<<<AGB, 256, 0, stream>>>(Th, cnt, csr_pad, dinv, b2, Hh, N_NODES);

    // --- output (sliced H) ---
    gemm_out_kernel<<<(N_NODES + 31) / 32, dim3(10, 32), 0, stream>>>(
        Hh, Wout, bout, out, N_NODES);
}

// Round 13
// 223.384 us; speedup vs baseline: 1.0413x; 1.0413x over previous
//
#include <hip/hip_runtime.h>
#include <hip/hip_fp16.h>

#define N_NODES 50000
#define N_EDGES 800000
#define F_INN   128
#define F_HID   96
#define F_OUTT  40
#define SLOTS   64    // padded-CSR slots/node; P(deg>=64 | Poisson(16)) ~ 2e-18

typedef _Float16 half8 __attribute__((ext_vector_type(8)));
typedef float    floatx4 __attribute__((ext_vector_type(4)));

// ---------------------------------------------------------------------------
// MFMA GEMM body: T[n][96] (fp16) = X[n x FI] @ W, via 16x16x32 f16.
// A = W^T tile (m=feature), B = node rows (n=node). 4 waves x 16 nodes = 64/blk.
// TIN = float (load+cvt) or __half (direct half8 load).
// SCALE: multiply the output row by dinv[node] in fp32 before the fp16 store
// (used for layer-2 so agg needs no per-edge dinv gather).
// LDS: single 26112B buffer; BT tile while computing, then (after a barrier)
// reused as the 13312B OUT staging area -> 6 blocks/CU instead of 4.
// ---------------------------------------------------------------------------
template <int FI, typename TIN, bool SCALE>
__device__ __forceinline__ void mfma_gemm_body(
        const TIN* __restrict__ X, const __half* __restrict__ BTg,
        const float* __restrict__ dinv, float4* __restrict__ Th4, int n, int bx) {
    __shared__ __half BTl[96 * 136];          // 26112 B; reused as OUT staging
    __half* OUTl = BTl;                       // [4*16][104] after the barrier
    int tid = threadIdx.x;
    {   // stage BT (1632 x 16B)
        const int4* s = reinterpret_cast<const int4*>(BTg);
        int4* d = reinterpret_cast<int4*>(BTl);
        for (int i = tid; i < 96 * 136 / 8; i += 256) d[i] = s[i];
    }
    __syncthreads();

    int lane = tid & 63, w = tid >> 6;
    int lm = lane & 15, q = lane >> 4;
    int base = bx * 64 + w * 16;
    int node = base + lm;
    int nclamp = min(node, n - 1);
    const TIN* Xrow = X + (size_t)nclamp * FI;

    floatx4 cf[6];
    #pragma unroll
    for (int t = 0; t < 6; ++t) cf[t] = (floatx4){0.f, 0.f, 0.f, 0.f};

    constexpr int KS = FI / 32;
    #pragma unroll
    for (int ks = 0; ks < KS; ++ks) {
        // B-operand: lane holds k = 32*ks + q*8 .. +7 of this node's row
        half8 bv;
        if constexpr (sizeof(TIN) == 4) {
            const float4* xr = reinterpret_cast<const float4*>(Xrow + 32 * ks + q * 8);
            float4 f0 = xr[0], f1 = xr[1];
            union { half8 v; __half2 h[4]; } b;
            b.h[0] = __floats2half2_rn(f0.x, f0.y);
            b.h[1] = __floats2half2_rn(f0.z, f0.w);
            b.h[2] = __floats2half2_rn(f1.x, f1.y);
            b.h[3] = __floats2half2_rn(f1.z, f1.w);
            bv = b.v;
        } else {
            bv = *reinterpret_cast<const half8*>(Xrow + 32 * ks + q * 8);
        }
        #pragma unroll
        for (int t = 0; t < 6; ++t) {
            half8 a = *reinterpret_cast<const half8*>(
                &BTl[(t * 16 + lm) * 136 + q * 8 + 32 * ks]);
            cf[t] = __builtin_amdgcn_mfma_f32_16x16x32_f16(a, bv, cf[t], 0, 0, 0);
        }
    }

    float dv = 1.0f;
    if constexpr (SCALE) dv = dinv[nclamp];   // lane's values are node=base+lm

    __syncthreads();   // all waves done reading BTl; safe to reuse as OUTl

    // Epilogue: D[row=q*4+r][col=lm] = out[feature = t*16+q*4+r][node=lm].
    __half* orow = OUTl + (w * 16 + lm) * 104;
    #pragma unroll
    for (int t = 0; t < 6; ++t) {
        union { int2 i2; __half2 h[2]; } u;
        u.h[0] = __floats2half2_rn(dv * cf[t][0], dv * cf[t][1]);
        u.h[1] = __floats2half2_rn(dv * cf[t][2], dv * cf[t][3]);
        *reinterpret_cast<int2*>(&orow[t * 16 + q * 4]) = u.i2;
    }
    // Same-wave LDS round-trip: coalesced fp16 row store (12 x float4 per node).
    #pragma unroll
    for (int R = 0; R < 3; ++R) {
        int nl = lane >> 2, c = (lane & 3) + 4 * R;
        float4 v = *reinterpret_cast<const float4*>(&OUTl[(w * 16 + nl) * 104 + c * 8]);
        int gn = base + nl;
        if (gn < n) Th4[(size_t)gn * 12 + c] = v;
    }
}

// ---------------------------------------------------------------------------
// Fused: count (blocks [0,nCB)) + gemm L1 (blocks [nCB,..)) — independent.
// Count: 2 edges/thread, returning atomics, COALESCED rank store.  With the
// padded CSR, rank IS the slot index -> no scan kernels exist at all.
// (~45us device-atomic floor, R4-R8; rides fused with gemm1.)
// ---------------------------------------------------------------------------
__global__ __launch_bounds__(256) void count_gemm1_kernel(
        const int* __restrict__ dst, int* __restrict__ cnt, int* __restrict__ rank,
        int e, const float* __restrict__ X, const __half* __restrict__ BT1,
        float4* __restrict__ Th4, int n, int nCB) {
    if ((int)blockIdx.x < nCB) {
        int i = blockIdx.x * 512 + threadIdx.x;
        int j = i + 256;
        bool bi = i < e, bj = j < e;
        int di = 0, dj = 0, ri, rj;
        if (bi) di = dst[i];
        if (bj) dj = dst[j];
        if (bi) ri = atomicAdd(&cnt[di], 1);
        if (bj) rj = atomicAdd(&cnt[dj], 1);
        if (bi) rank[i] = ri;
        if (bj) rank[j] = rj;
    } else {
        mfma_gemm_body<F_INN, float, false>(X, BT1, nullptr, Th4, n, blockIdx.x - nCB);
    }
}

template <int FI, typename TIN, bool SCALE>
__global__ __launch_bounds__(256) void mfma_gemm_kernel(
        const TIN* __restrict__ X, const __half* __restrict__ BTg,
        const float* __restrict__ dinv, float4* __restrict__ Th4, int n) {
    mfma_gemm_body<FI, TIN, SCALE>(X, BTg, dinv, Th4, n, blockIdx.x);
}

// ---------------------------------------------------------------------------
// Weight transpose + fp16: W[K x 96] -> BT[96][136] (pad 8). W1 & W2 together.
// ---------------------------------------------------------------------------
__global__ void wt_kernel(const float* __restrict__ W1, const float* __restrict__ W2,
                          __half* __restrict__ BT1, __half* __restrict__ BT2) {
    int i = blockIdx.x * 256 + threadIdx.x;
    if (i < 96 * 128) {
        int j = i / 128, k = i - j * 128;
        BT1[j * 136 + k] = __float2half(W1[k * 96 + j]);
    } else if (i < 96 * 128 + 96 * 96) {
        int t = i - 96 * 128;
        int j = t / 96, k = t - j * 96;
        BT2[j * 136 + k] = __float2half(W2[k * 96 + j]);
    }
}

// ---------------------------------------------------------------------------
// Fused: atomic-free padded-CSR fill (blocks [0,nFB)) + dinv/T pre-scale
// (blocks [nFB,..)) — independent, both depend only on the count pass.
// Fill: csr_pad[dst*64 + rank] = src (one scattered 4B store, no atomics).
// Scale: dinv[i] = rsqrt(deg+1); T[node] *= dinv[node] so agg needs no
// per-edge dinv gather.
// ---------------------------------------------------------------------------
__global__ __launch_bounds__(256) void fill_scale_kernel(
        const int* __restrict__ src, const int* __restrict__ dst,
        const int* __restrict__ rank, int* __restrict__ csr_pad,
        const int* __restrict__ cnt, float* __restrict__ dinv,
        float4* __restrict__ Th4, int e, int n, int nFB) {
    if ((int)blockIdx.x < nFB) {
        int i = blockIdx.x * 256 + threadIdx.x;
        if (i >= e) return;
        int r = rank[i];
        if (r < SLOTS) csr_pad[dst[i] * SLOTS + r] = src[i];
    } else {
        int i = (blockIdx.x - nFB) * 256 + threadIdx.x;   // float4 index
        if (i < n) dinv[i] = rsqrtf((float)min(cnt[i], SLOTS) + 1.0f);
        if (i >= n * 12) return;
        int node = i / 12;
        float s = rsqrtf((float)min(cnt[node], SLOTS) + 1.0f);
        union { float4 f4; __half2 h[4]; } u;
        u.f4 = Th4[i];
        #pragma unroll
        for (int q = 0; q < 4; ++q) {
            float2 t = __half22float2(u.h[q]);
            u.h[q] = __floats2half2_rn(s * t.x, s * t.y);
        }
        Th4[i] = u.f4;
    }
}

// ---------------------------------------------------------------------------
// Aggregation: one wave per node; T is PRE-SCALED fp16 (dinv[s]*T[s]), padded
// CSR: row = csr_pad + node*64, deg = cnt[node] (wave-uniform scalar loads).
// H[d] = relu(dinv[d]*(Σ T[s] + T[d]) + b).  Output fp16.
// ---------------------------------------------------------------------------
__global__ __launch_bounds__(256) void agg_kernel(
        const __half2* __restrict__ T, const int* __restrict__ cnt,
        const int* __restrict__ csr_pad, const float* __restrict__ dinv,
        const float* __restrict__ bias, __half2* __restrict__ H, int n) {
    int lane = threadIdx.x & 63;
    int node = __builtin_amdgcn_readfirstlane(blockIdx.x * 4 + (threadIdx.x >> 6));
    if (node >= n) return;
    int fl = min(lane, 47);                    // lanes 48..63 duplicate lane 47

    float dn = dinv[node];
    float2 self = __half22float2(T[(size_t)node * 48 + fl]);  // already dinv[d]-scaled
    float accx = self.x, accy = self.y;

    const int* row = csr_pad + (size_t)node * SLOTS;
    int deg = min(cnt[node], SLOTS);
    int idx = 0;
    for (; idx + 8 <= deg; idx += 8) {
        int s[8];
        #pragma unroll
        for (int u = 0; u < 8; ++u) s[u] = row[idx + u];
        float2 f[8];
        #pragma unroll
        for (int u = 0; u < 8; ++u) f[u] = __half22float2(T[(size_t)s[u] * 48 + fl]);
        #pragma unroll
        for (int u = 0; u < 8; ++u) {
            accx += f[u].x;
            accy += f[u].y;
        }
    }
    for (; idx < deg; ++idx) {
        int s = row[idx];
        float2 f = __half22float2(T[(size_t)s * 48 + fl]);
        accx += f.x;
        accy += f.y;
    }
    if (lane < 48) {
        float2 b = reinterpret_cast<const float2*>(bias)[lane];
        float ox = fmaxf(fmaf(dn, accx, b.x), 0.f);
        float oy = fmaxf(fmaf(dn, accy, b.y), 0.f);
        H[(size_t)node * 48 + lane] = __floats2half2_rn(ox, oy);
    }
}

// ---------------------------------------------------------------------------
// Output GEMM: out[n x 40] = H[n x 96](fp16) @ W[96 x 40] + bias (fp32 acc).
// ---------------------------------------------------------------------------
__global__ __launch_bounds__(320) void gemm_out_kernel(
        const __half2* __restrict__ A, const float* __restrict__ W,
        const float* __restrict__ bias, float* __restrict__ C, int n) {
    __shared__ float Wlds[96 * 40];
    int tid = threadIdx.y * 10 + threadIdx.x;
    for (int i = tid; i < 96 * 10; i += 320)
        reinterpret_cast<float4*>(Wlds)[i] = reinterpret_cast<const float4*>(W)[i];
    __syncthreads();

    int j    = threadIdx.x * 4;
    int node = blockIdx.x * 32 + threadIdx.y;
    int nc   = min(node, n - 1);
    const __half2* Ah = A + (size_t)nc * 48;
    float4 acc = make_float4(0.f, 0.f, 0.f, 0.f);
    for (int k2 = 0; k2 < 48; k2 += 2) {          // k = 2*k2 .. 2*k2+3
        float2 a01 = __half22float2(Ah[k2]);
        float2 a23 = __half22float2(Ah[k2 + 1]);
        int k = 2 * k2;
        float4 w0 = *reinterpret_cast<const float4*>(Wlds + (k + 0) * 40 + j);
        float4 w1 = *reinterpret_cast<const float4*>(Wlds + (k + 1) * 40 + j);
        float4 w2 = *reinterpret_cast<const float4*>(Wlds + (k + 2) * 40 + j);
        float4 w3 = *reinterpret_cast<const float4*>(Wlds + (k + 3) * 40 + j);
        acc.x += a01.x * w0.x + a01.y * w1.x + a23.x * w2.x + a23.y * w3.x;
        acc.y += a01.x * w0.y + a01.y * w1.y + a23.x * w2.y + a23.y * w3.y;
        acc.z += a01.x * w0.z + a01.y * w1.z + a23.x * w2.z + a23.y * w3.z;
        acc.w += a01.x * w0.w + a01.y * w1.w + a23.x * w2.w + a23.y * w3.w;
    }
    if (node < n) {
        float4 b = *reinterpret_cast<const float4*>(bias + j);
        acc.x += b.x; acc.y += b.y; acc.z += b.z; acc.w += b.w;
        *reinterpret_cast<float4*>(C + (size_t)node * 40 + j) = acc;
    }
}

// ---------------------------------------------------------------------------

extern "C" void kernel_launch(void* const* d_in, const int* in_sizes, int n_in,
                              void* d_out, int out_size, void* d_ws, size_t ws_size,
                              hipStream_t stream) {
    const float* x    = (const float*)d_in[0];
    const int*   ei   = (const int*)d_in[1];
    const float* W1   = (const float*)d_in[2];
    const float* b1   = (const float*)d_in[3];
    const float* W2   = (const float*)d_in[4];
    const float* b2   = (const float*)d_in[5];
    const float* Wout = (const float*)d_in[6];
    const float* bout = (const float*)d_in[7];
    float*       out  = (float*)d_out;

    const int* src = ei;            // edge_index[0]
    const int* dst = ei + N_EDGES;  // edge_index[1]

    char* ws = (char*)d_ws;
    size_t off = 0;
    auto alloc = [&](size_t bytes) {
        size_t o = off;
        off = (off + bytes + 511) & ~(size_t)511;
        return (void*)(ws + o);
    };
    int*     cnt       = (int*)    alloc((size_t)N_NODES * sizeof(int));
    float*   dinv      = (float*)  alloc(N_NODES * sizeof(float));
    int*     rank      = (int*)    alloc((size_t)N_EDGES * sizeof(int));
    int*     csr_pad   = (int*)    alloc((size_t)N_NODES * SLOTS * sizeof(int));
    __half*  BT1       = (__half*) alloc((size_t)96 * 136 * sizeof(__half));
    __half*  BT2       = (__half*) alloc((size_t)96 * 136 * sizeof(__half));
    __half2* Th        = (__half2*)alloc((size_t)N_NODES * 48 * sizeof(__half2));
    __half2* Hh        = (__half2*)alloc((size_t)N_NODES * 48 * sizeof(__half2));

    const int CB2 = (N_EDGES + 511) / 512;       // 1563 count blocks (2 edges/thr)
    const int FB  = (N_EDGES + 255) / 256;       // 3125 fill blocks
    const int SB  = (N_NODES * 12 + 255) / 256;  // 2344 scale blocks
    const int GB  = (N_NODES + 63) / 64;         // 782 gemm blocks
    const int AB  = (N_NODES + 3) / 4;           // 12500 agg blocks

    // --- prep ---
    hipMemsetAsync(cnt, 0, (size_t)N_NODES * sizeof(int), stream);
    wt_kernel<<<(96 * 128 + 96 * 96 + 255) / 256, 256, 0, stream>>>(W1, W2, BT1, BT2);

    // --- fused: edge count (rank = padded-CSR slot) + layer-1 GEMM ---
    count_gemm1_kernel<<<CB2 + GB, 256, 0, stream>>>(
        dst, cnt, rank, N_EDGES, x, BT1, (float4*)Th, N_NODES, CB2);

    // --- fused: atomic-free CSR fill + dinv/T pre-scale ---
    fill_scale_kernel<<<FB + SB, 256, 0, stream>>>(
        src, dst, rank, csr_pad, cnt, dinv, (float4*)Th, N_EDGES, N_NODES, FB);

    // --- layer 1 aggregation -> H (fp16) ---
    agg_kernel<<<AB, 256, 0, stream>>>(
        Th, cnt, csr_pad, dinv, b1, Hh, N_NODES);

    // --- layer 2: GEMM (fp16 in, dinv-scaled out) + aggregation ---
    mfma_gemm_kernel<F_HID, __half, true><<<GB, 256, 0, stream>>>(
        (const __half*)Hh, BT2, dinv, (float4*)Th, N_NODES);
    agg_kernel<<<AB, 256, 0, stream>>>(
        Th, cnt, csr_pad, dinv, b2, Hh, N_NODES);

    // --- output ---
    gemm_out_kernel<<<(N_NODES + 31) / 32, dim3(10, 32), 0, stream>>>(
        Hh, Wout, bout, out, N_NODES);
}